// Round 11
// baseline (10329.596 us; speedup 1.0000x reference)
//
#include <hip/hip_runtime.h>

// Problem constants (fixed by the reference)
constexpr int Bc = 64;      // batch
constexpr int Tc = 2048;    // time steps
constexpr int Ic = 3;       // input dim
constexpr int Hc = 512;     // hidden
constexpr float AL = 0.2f;  // ALPHA
constexpr float NS = 0.05f; // NOISE_STD

// Decomposition (round-8 proven): 16 h-slices (HS=32) x 16 batch-groups (G=4).
constexpr int G   = 4;
constexpr int HS  = 32;
constexpr int PLS = 130;   // pl row stride, layout [wave][ob*32+ohl] (conflict-free)

// d_ws layout:
//   [0, 1MB)       WH fp32 [512 h][512 k]
//   [1MB, 1.5MB)   fast rbuf u64 [16 gb][2 par][4 b][512 h] = {tag<<32|f32}, plain stores
//   [1.5MB, 2MB)   slow rbuf u64 (agent-scope stores -> MALL; guaranteed visible)
//   [2MB, 10MB)    part fp32 [16 s][64 b][2048 t]
//   [10MB, +4)     epoch u32 (monotonic across calls; never reset)
constexpr size_t WS_WH    = 0;
constexpr size_t WS_FAST  = 1u << 20;
constexpr size_t WS_SLOW  = WS_FAST + (512u << 10);
constexpr size_t WS_PART  = 2u << 20;
constexpr size_t WS_EPOCH = 10u << 20;
constexpr size_t WS_NEED  = WS_EPOCH + 64;

// ---------------------------------------------------------------------------
__global__ void prep_wh(const float* __restrict__ m, const float* __restrict__ n,
                        const float* __restrict__ rn, float* __restrict__ WH, int R) {
    int id = blockIdx.x * 256 + threadIdx.x;
    if (id >= Hc * Hc) return;
    int h = id >> 9;
    int k = id & (Hc - 1);
    float acc = rn[h * Hc + k];
    for (int r = 0; r < R; ++r)
        acc = fmaf(m[h * R + r], n[k * R + r] * (1.0f / Hc), acc);
    WH[id] = acc;                               // WH[h][k]
}

__global__ void prep_wt(const float* __restrict__ m, const float* __restrict__ n,
                        const float* __restrict__ rn, float* __restrict__ WT, int R) {
    int id = blockIdx.x * 256 + threadIdx.x;
    if (id >= Hc * Hc) return;
    int k = id >> 9;
    int h = id & (Hc - 1);
    float acc = rn[h * Hc + k];
    for (int r = 0; r < R; ++r)
        acc = fmaf(m[h * R + r], n[k * R + r] * (1.0f / Hc), acc);
    WT[id] = acc;                               // WT[k][h] (fallback)
}

__global__ void bump_epoch(unsigned* e) {
    if (threadIdx.x == 0 && blockIdx.x == 0) *e += 4096u;
}

// --- asm helpers ------------------------------------------------------------
// Fast publish: plain 8B store (write-through L1 -> XCD L2).
__device__ __forceinline__ void st_u64(unsigned long long* p, unsigned long long v) {
    asm volatile("global_store_dwordx2 %0, %1, off" :: "v"(p), "v"(v) : "memory");
}
// 64B pipelined sc0 chunk load (L1-bypassing): 4 dwordx4 in flight, ONE waitcnt.
// Each dwordx4 = 2 tagged words: (x=val0,y=tag0,z=val1,w=tag1).
__device__ __forceinline__ void ld64_sc0(const unsigned long long* p,
        float4& A, float4& B, float4& C, float4& D) {
    asm volatile(
        "global_load_dwordx4 %0, %4, off sc0\n\t"
        "global_load_dwordx4 %1, %4, off offset:16 sc0\n\t"
        "global_load_dwordx4 %2, %4, off offset:32 sc0\n\t"
        "global_load_dwordx4 %3, %4, off offset:48 sc0\n\t"
        "s_waitcnt vmcnt(0)"
        : "=&v"(A), "=&v"(B), "=&v"(C), "=&v"(D)
        : "v"(p) : "memory");
}

// NOTE: macro parameter names must not collide with vector members (.x/.y/.z/.w)
#define DOT4(acc, W4, R4) \
    acc = fmaf((W4).x, (R4).x, fmaf((W4).y, (R4).y, \
          fmaf((W4).z, (R4).z, fmaf((W4).w, (R4).w, acc))))

// ---------------------------------------------------------------------------
// Main kernel: 256 blocks x 1024 threads. Compute core = round 8 (proven).
// Transport: self-tagged dual-publish (r9, proven non-hanging) consumed by
// CHUNKED pipelined bulk polls: 120 poller lanes x 16 words, 64B sc0 chunks
// with all-8-tags validation; agent-scope chunk every 8th retry (progress
// guaranteed on any XCD placement; every word self-verified -> no stale risk).
// ---------------------------------------------------------------------------
__global__ __launch_bounds__(1024)
void rnn16b(const float* __restrict__ input, const float* __restrict__ noise,
            const float* __restrict__ w_i, const float* __restrict__ s_i,
            const float* __restrict__ WH, const float* __restrict__ w_o,
            const float* __restrict__ s_o, const float* __restrict__ h0,
            float* __restrict__ part,
            unsigned long long* __restrict__ fbuf,
            unsigned long long* __restrict__ sbuf,
            const unsigned* __restrict__ epoch) {
    __shared__ float rp[2 * G * Hc];     // [parity][b][512]
    __shared__ float pl[16 * PLS];       // [wave][ob*32+ohl] matvec partials

    const int tid   = threadIdx.x;
    const int s     = blockIdx.x >> 4;   // h-slice 0..15
    const int gb    = blockIdx.x & 15;   // batch group 0..15
    const int kc    = tid >> 4;          // k-chunk 0..63 (8 k each)
    const int hg    = tid & 15;          // row-pair 0..15
    const int hbase = s * HS;
    const int b0    = gb * G;
    const unsigned ep = *epoch;

    // --- W tile: 2 rows x 8 k = 16 floats in registers (round-8 proven) ---
    const float* Wp0 = WH + (size_t)(hbase + 2 * hg + 0) * Hc + kc * 8;
    const float* Wp1 = WH + (size_t)(hbase + 2 * hg + 1) * Hc + kc * 8;
    const float4 w00 = *(const float4*)(Wp0 + 0);
    const float4 w01 = *(const float4*)(Wp0 + 4);
    const float4 w10 = *(const float4*)(Wp1 + 0);
    const float4 w11 = *(const float4*)(Wp1 + 4);

    // --- r_0 into parity-0 (same for all 4 batches) ---
    if (tid < Hc) {
        const float rv0 = tanhf(h0[tid]);
        #pragma unroll
        for (int b = 0; b < G; ++b) rp[b * Hc + tid] = rv0;
    }

    // --- owners: tid<128, ob = tid>>5 (batch), ohl = tid&31 (row) ---
    const bool own = (tid < 128);
    const int  ob  = tid >> 5;
    const int  ohl = tid & 31;
    const int  ohm = hbase + ohl;
    float hstate = 0.f, wi0 = 0.f, wi1 = 0.f, wi2 = 0.f, wo_own = 0.f;
    const float* noise_b = nullptr;
    const float* inp_b   = nullptr;
    float nz = 0.f, i0 = 0.f, i1 = 0.f, i2 = 0.f;
    if (own) {
        hstate = h0[ohm];
        wi0 = w_i[0 * Hc + ohm] * s_i[0];
        wi1 = w_i[1 * Hc + ohm] * s_i[1];
        wi2 = w_i[2 * Hc + ohm] * s_i[2];
        wo_own = w_o[ohm] * s_o[0] * (1.0f / Hc);
        noise_b = noise + (size_t)(b0 + ob) * Tc * Hc;
        inp_b   = input + (size_t)(b0 + ob) * Tc * Ic;
        nz = noise_b[ohm];
        i0 = inp_b[0]; i1 = inp_b[1]; i2 = inp_b[2];
    }

    // --- pollers: 120 lanes (waves 13-14), each 16 foreign words (2 chunks) ---
    const bool pol = (tid >= 832 && tid < 952);
    int pb = 0, pfs = 0, pco = 0;
    if (pol) {
        const int idx  = tid - 832;
        const int pair = idx / 60;      // 0..1: which 16-word half
        const int rem  = idx % 60;
        pb = rem / 15;                  // foreign batch lane 0..3
        int pfs0 = rem % 15;
        pfs = pfs0 + ((pfs0 >= s) ? 1 : 0);  // skip own slice
        pco = pair * 2;                 // starting chunk (2 chunks of 8 words)
    }

    unsigned long long* fb_g = fbuf + (size_t)gb * (2 * G * Hc);
    unsigned long long* sb_g = sbuf + (size_t)gb * (2 * G * Hc);
    float* part_b = part + ((size_t)s * Bc + b0) * Tc;

    __syncthreads();

    for (int t = 0; t < Tc; ++t) {
        const int par  = t & 1;
        const int par1 = (t + 1) & 1;

        // owners: prefetch next step's drive
        const int tn = (t + 1 < Tc) ? t + 1 : t;
        float nz_n = 0.f, i0n = 0.f, i1n = 0.f, i2n = 0.f;
        if (own) {
            nz_n = noise_b[(size_t)tn * Hc + ohm];
            i0n = inp_b[tn * Ic + 0];
            i1n = inp_b[tn * Ic + 1];
            i2n = inp_b[tn * Ic + 2];
        }

        // --- matvec: W in regs, r broadcast from LDS (round-8 verbatim) ---
        const float* rbp = rp + par * (G * Hc) + kc * 8;
        float a00 = 0.f, a01 = 0.f, a02 = 0.f, a03 = 0.f;
        float a10 = 0.f, a11 = 0.f, a12 = 0.f, a13 = 0.f;
        {
            const float4 r0 = *(const float4*)(rbp + 0 * Hc);
            const float4 r1 = *(const float4*)(rbp + 1 * Hc);
            const float4 r2 = *(const float4*)(rbp + 2 * Hc);
            const float4 r3 = *(const float4*)(rbp + 3 * Hc);
            DOT4(a00, w00, r0); DOT4(a01, w00, r1); DOT4(a02, w00, r2); DOT4(a03, w00, r3);
            DOT4(a10, w10, r0); DOT4(a11, w10, r1); DOT4(a12, w10, r2); DOT4(a13, w10, r3);
        }
        {
            const float4 r0 = *(const float4*)(rbp + 0 * Hc + 4);
            const float4 r1 = *(const float4*)(rbp + 1 * Hc + 4);
            const float4 r2 = *(const float4*)(rbp + 2 * Hc + 4);
            const float4 r3 = *(const float4*)(rbp + 3 * Hc + 4);
            DOT4(a00, w01, r0); DOT4(a01, w01, r1); DOT4(a02, w01, r2); DOT4(a03, w01, r3);
            DOT4(a10, w11, r0); DOT4(a11, w11, r1); DOT4(a12, w11, r2); DOT4(a13, w11, r3);
        }
        #define RED2(a) { a += __shfl_xor(a, 16, 64); a += __shfl_xor(a, 32, 64); }
        RED2(a00) RED2(a01) RED2(a02) RED2(a03)
        RED2(a10) RED2(a11) RED2(a12) RED2(a13)
        #undef RED2

        // writers: lane hg of each wave, TRANSPOSED pl layout (conflict-free)
        if ((tid & 63) < 16) {
            float* plw = pl + (tid >> 6) * PLS;
            const int r0i = 2 * hg, r1i = 2 * hg + 1;
            plw[0 * 32 + r0i] = a00; plw[1 * 32 + r0i] = a01;
            plw[2 * 32 + r0i] = a02; plw[3 * 32 + r0i] = a03;
            plw[0 * 32 + r1i] = a10; plw[1 * 32 + r1i] = a11;
            plw[2 * 32 + r1i] = a12; plw[3 * 32 + r1i] = a13;
        }
        __syncthreads();                                   // B1: pl ready

        const unsigned want = ep + (unsigned)(t + 1);
        unsigned long long* fslot = fb_g + (size_t)par1 * (G * Hc);
        unsigned long long* sslot = sb_g + (size_t)par1 * (G * Hc);
        float* wp_ = rp + par1 * (G * Hc);

        if (own) {
            float y = 0.f;
            #pragma unroll
            for (int w = 0; w < 16; ++w) y += pl[w * PLS + ob * 32 + ohl];
            const float di = i0 * wi0 + i1 * wi1 + i2 * wi2;
            hstate = hstate + (NS * nz + AL * di) + AL * (y - hstate);
            const float rv = tanhf(hstate);
            const unsigned long long word =
                ((unsigned long long)want << 32) | (unsigned long long)__float_as_uint(rv);
            st_u64(&fslot[ob * Hc + ohm], word);            // fast: XCD L2
            __hip_atomic_store(&sslot[ob * Hc + ohm], word,
                               __ATOMIC_RELAXED, __HIP_MEMORY_SCOPE_AGENT); // slow: MALL
            wp_[ob * Hc + ohm] = rv;

            // output partial (off the exchange critical path)
            float pr = rv * wo_own;
            #pragma unroll
            for (int m = 16; m; m >>= 1) pr += __shfl_xor(pr, m, 32);
            if ((tid & 31) == 0) part_b[(size_t)ob * Tc + t] = pr;
        }

        // --- pollers: per 8-word chunk, retry pipelined sc0 bulk; every 8th
        //     retry reads the agent-published slow buffer (guaranteed visible).
        //     Every word carries its own tag -> no ordering/eviction hazard.
        if (pol) {
            const size_t base = (size_t)pb * Hc + (size_t)pfs * HS;
            #pragma unroll
            for (int cc = 0; cc < 2; ++cc) {
                const int c = pco + cc;
                const unsigned long long* fp = &fslot[base + c * 8];
                const unsigned long long* sp = &sslot[base + c * 8];
                float4* dst = (float4*)&wp_[base + c * 8];
                int tries = 0;
                for (;;) {
                    if ((tries & 7) != 7) {
                        float4 A, B, C4, D;
                        ld64_sc0(fp, A, B, C4, D);
                        if (__float_as_uint(A.y) == want && __float_as_uint(A.w) == want &&
                            __float_as_uint(B.y) == want && __float_as_uint(B.w) == want &&
                            __float_as_uint(C4.y) == want && __float_as_uint(C4.w) == want &&
                            __float_as_uint(D.y) == want && __float_as_uint(D.w) == want) {
                            dst[0] = make_float4(A.x, A.z, B.x, B.z);
                            dst[1] = make_float4(C4.x, C4.z, D.x, D.z);
                            break;
                        }
                    } else {
                        unsigned long long wv[8];
                        bool ok = true;
                        #pragma unroll
                        for (int j = 0; j < 8; ++j) {
                            wv[j] = __hip_atomic_load(sp + j, __ATOMIC_RELAXED,
                                                      __HIP_MEMORY_SCOPE_AGENT);
                            ok = ok && ((unsigned)(wv[j] >> 32) == want);
                        }
                        if (ok) {
                            dst[0] = make_float4(__uint_as_float((unsigned)wv[0]),
                                                 __uint_as_float((unsigned)wv[1]),
                                                 __uint_as_float((unsigned)wv[2]),
                                                 __uint_as_float((unsigned)wv[3]));
                            dst[1] = make_float4(__uint_as_float((unsigned)wv[4]),
                                                 __uint_as_float((unsigned)wv[5]),
                                                 __uint_as_float((unsigned)wv[6]),
                                                 __uint_as_float((unsigned)wv[7]));
                            break;
                        }
                    }
                    ++tries;
                }
            }
        }
        __syncthreads();                                   // B2: r_{t+1} ready

        nz = nz_n; i0 = i0n; i1 = i1n; i2 = i2n;
    }
}

// ---------------------------------------------------------------------------
// Epilogue: out[b][t] = sum over 16 slices of part[s][b][t]
// ---------------------------------------------------------------------------
__global__ void out_reduce16(const float* __restrict__ part, float* __restrict__ out) {
    const int id = blockIdx.x * 256 + threadIdx.x;
    if (id >= Bc * Tc) return;
    const int b = id >> 11, t = id & (Tc - 1);
    float sm = 0.f;
    #pragma unroll
    for (int sl = 0; sl < 16; ++sl)
        sm += part[((size_t)sl * Bc + b) * Tc + t];
    out[id] = sm;
}

// ---------------------------------------------------------------------------
// Fallback (round-1 kernel) if d_ws is too small — safety net.
// ---------------------------------------------------------------------------
__launch_bounds__(512)
__global__ void rnn_scan_fb(const float* __restrict__ input, const float* __restrict__ noise,
                            const float* __restrict__ w_i, const float* __restrict__ s_i,
                            const float* __restrict__ WT, const float* __restrict__ w_o,
                            const float* __restrict__ s_o, const float* __restrict__ h0,
                            float* __restrict__ out) {
    __shared__ float r_lds[Hc];
    __shared__ float pl[4][Hc];
    __shared__ float wi_lds[Ic][Hc];
    __shared__ float red[8];

    const int tid = threadIdx.x;
    const int b   = blockIdx.x;
    const int g   = tid >> 7;
    const int j   = tid & 127;

    for (int i = 0; i < Ic; ++i) wi_lds[i][tid] = w_i[i * Hc + tid] * s_i[i];

    float h = h0[tid];
    float r_cur = tanhf(h);
    const float wo_h = w_o[tid] * s_o[0] * (1.0f / Hc);
    const float* noise_b = noise + (size_t)b * Tc * Hc;
    const float* inp_b   = input + (size_t)b * Tc * Ic;
    float nz = noise_b[tid];
    float i0 = inp_b[0], i1 = inp_b[1], i2 = inp_b[2];
    const float* Wg = WT + (g * 128) * Hc + 4 * j;
    const float* rg = r_lds + g * 128;
    __syncthreads();

    for (int t = 0; t < Tc; ++t) {
        const int tn = (t + 1 < Tc) ? t + 1 : t;
        const float nz_n = noise_b[(size_t)tn * Hc + tid];
        const float i0n = inp_b[tn * Ic + 0];
        const float i1n = inp_b[tn * Ic + 1];
        const float i2n = inp_b[tn * Ic + 2];

        r_lds[tid] = r_cur;
        __syncthreads();
        float a0 = 0.f, a1 = 0.f, a2 = 0.f, a3 = 0.f;
        #pragma unroll 4
        for (int kk = 0; kk < 128; kk += 4) {
            const float4 rv = *(const float4*)(rg + kk);
            const float4 w0 = *(const float4*)(Wg + (kk + 0) * Hc);
            const float4 w1 = *(const float4*)(Wg + (kk + 1) * Hc);
            const float4 w2 = *(const float4*)(Wg + (kk + 2) * Hc);
            const float4 w3 = *(const float4*)(Wg + (kk + 3) * Hc);
            a0 = fmaf(rv.x, w0.x, a0); a0 = fmaf(rv.y, w1.x, a0);
            a0 = fmaf(rv.z, w2.x, a0); a0 = fmaf(rv.w, w3.x, a0);
            a1 = fmaf(rv.x, w0.y, a1); a1 = fmaf(rv.y, w1.y, a1);
            a1 = fmaf(rv.z, w2.y, a1); a1 = fmaf(rv.w, w3.y, a1);
            a2 = fmaf(rv.x, w0.z, a2); a2 = fmaf(rv.y, w1.z, a2);
            a2 = fmaf(rv.z, w2.z, a2); a2 = fmaf(rv.w, w3.z, a2);
            a3 = fmaf(rv.x, w0.w, a3); a3 = fmaf(rv.y, w1.w, a3);
            a3 = fmaf(rv.z, w2.w, a3); a3 = fmaf(rv.w, w3.w, a3);
        }
        *(float4*)&pl[g][4 * j] = make_float4(a0, a1, a2, a3);
        __syncthreads();

        const float y  = pl[0][tid] + pl[1][tid] + pl[2][tid] + pl[3][tid];
        const float di = i0 * wi_lds[0][tid] + i1 * wi_lds[1][tid] + i2 * wi_lds[2][tid];
        h = h + (NS * nz + AL * di) + AL * (y - h);
        r_cur = tanhf(h);

        float p = r_cur * wo_h;
        #pragma unroll
        for (int off = 32; off; off >>= 1) p += __shfl_xor(p, off, 64);
        if ((tid & 63) == 0) red[tid >> 6] = p;
        __syncthreads();
        if (tid == 0)
            out[(size_t)b * Tc + t] = red[0] + red[1] + red[2] + red[3] +
                                      red[4] + red[5] + red[6] + red[7];
        nz = nz_n; i0 = i0n; i1 = i1n; i2 = i2n;
    }
}

extern "C" void kernel_launch(void* const* d_in, const int* in_sizes, int n_in,
                              void* d_out, int out_size, void* d_ws, size_t ws_size,
                              hipStream_t stream) {
    (void)n_in; (void)out_size;
    const float* input     = (const float*)d_in[0];
    const float* noise     = (const float*)d_in[1];
    const float* w_i       = (const float*)d_in[2];
    const float* s_i       = (const float*)d_in[3];
    const float* m_rec     = (const float*)d_in[4];
    const float* n_rec     = (const float*)d_in[5];
    const float* rec_noise = (const float*)d_in[6];
    const float* w_o       = (const float*)d_in[7];
    const float* s_o       = (const float*)d_in[8];
    const float* h0        = (const float*)d_in[9];
    float* out = (float*)d_out;

    const int R = in_sizes[4] / Hc;
    char* ws = (char*)d_ws;

    if (ws_size >= WS_NEED) {
        float*    WH   = (float*)(ws + WS_WH);
        unsigned long long* fbuf = (unsigned long long*)(ws + WS_FAST);
        unsigned long long* sbuf = (unsigned long long*)(ws + WS_SLOW);
        float*    part = (float*)(ws + WS_PART);
        unsigned* epoch = (unsigned*)(ws + WS_EPOCH);

        bump_epoch<<<1, 1, 0, stream>>>(epoch);   // stale tags can never match
        prep_wh<<<(Hc * Hc + 255) / 256, 256, 0, stream>>>(m_rec, n_rec, rec_noise, WH, R);
        rnn16b<<<256, 1024, 0, stream>>>(input, noise, w_i, s_i, WH, w_o, s_o, h0,
                                         part, fbuf, sbuf, epoch);
        out_reduce16<<<(Bc * Tc + 255) / 256, 256, 0, stream>>>(part, out);
    } else {
        float* WT = (float*)(ws + WS_WH);
        prep_wt<<<(Hc * Hc + 255) / 256, 256, 0, stream>>>(m_rec, n_rec, rec_noise, WT, R);
        rnn_scan_fb<<<Bc, 512, 0, stream>>>(input, noise, w_i, s_i, WT, w_o, s_o, h0, out);
    }
}

// Round 12
// 6275.574 us; speedup vs baseline: 1.6460x; 1.6460x over previous
//
#include <hip/hip_runtime.h>

// Problem constants (fixed by the reference)
constexpr int Bc = 64;      // batch
constexpr int Tc = 2048;    // time steps
constexpr int Ic = 3;       // input dim
constexpr int Hc = 512;     // hidden
constexpr float AL = 0.2f;  // ALPHA
constexpr float NS = 0.05f; // NOISE_STD

// Geometry (round-8 proven): 16 h-slices (HS=32) x 16 batch-groups (G=4).
constexpr int G   = 4;
constexpr int HS  = 32;
constexpr int PLS = 130;   // pl row stride, layout [wave][ob*32+ohl]

// d_ws layout:
//   [0, 1MB)      WH fp32 [512 h][512 k]
//   [1MB, 1.5MB)  sbuf u64 [16 gb][2 par][4 b][512 h] = {tag<<32|f32}, agent/MALL
//   [2MB, 10MB)   part fp32 [16 s][64 b][2048 t]
//   [10MB, +4)    epoch u32 (monotonic across calls; never reset)
constexpr size_t WS_WH    = 0;
constexpr size_t WS_SBUF  = 1u << 20;
constexpr size_t WS_PART  = 2u << 20;
constexpr size_t WS_EPOCH = 10u << 20;
constexpr size_t WS_NEED  = WS_EPOCH + 64;

// ---------------------------------------------------------------------------
__global__ void prep_wh(const float* __restrict__ m, const float* __restrict__ n,
                        const float* __restrict__ rn, float* __restrict__ WH, int R) {
    int id = blockIdx.x * 256 + threadIdx.x;
    if (id >= Hc * Hc) return;
    int h = id >> 9;
    int k = id & (Hc - 1);
    float acc = rn[h * Hc + k];
    for (int r = 0; r < R; ++r)
        acc = fmaf(m[h * R + r], n[k * R + r] * (1.0f / Hc), acc);
    WH[id] = acc;                               // WH[h][k]
}

__global__ void prep_wt(const float* __restrict__ m, const float* __restrict__ n,
                        const float* __restrict__ rn, float* __restrict__ WT, int R) {
    int id = blockIdx.x * 256 + threadIdx.x;
    if (id >= Hc * Hc) return;
    int k = id >> 9;
    int h = id & (Hc - 1);
    float acc = rn[h * Hc + k];
    for (int r = 0; r < R; ++r)
        acc = fmaf(m[h * R + r], n[k * R + r] * (1.0f / Hc), acc);
    WT[id] = acc;                               // WT[k][h] (fallback)
}

__global__ void bump_epoch(unsigned* e) {
    if (threadIdx.x == 0 && blockIdx.x == 0) *e += 4096u;
}

// NOTE: macro parameter names must not collide with vector members (.x/.y/.z/.w)
#define DOT4(acc, W4, R4) \
    acc = fmaf((W4).x, (R4).x, fmaf((W4).y, (R4).y, \
          fmaf((W4).z, (R4).z, fmaf((W4).w, (R4).w, acc))))

// ---------------------------------------------------------------------------
// Main kernel: 256 blocks x 1024 threads.
// Compute core = round 8 (W tile in regs via OPAQUE asm loads).
// Transport: owners publish self-tagged u64 agent-scope (MALL, proven plane).
// Consumers: 4 sweeper waves; lane i owns words {j*256+i, j=0..7} -> every
// burst is 8 pipelined, fully COALESCED 2KB streams with ONE waitcnt.
// Tag+parity (skew<=1, proven r8) + epoch tags (r9) -> no hang, no staleness.
// ---------------------------------------------------------------------------
__global__ __launch_bounds__(1024)
void rnn16s(const float* __restrict__ input, const float* __restrict__ noise,
            const float* __restrict__ w_i, const float* __restrict__ s_i,
            const float* __restrict__ WH, const float* __restrict__ w_o,
            const float* __restrict__ s_o, const float* __restrict__ h0,
            float* __restrict__ part,
            unsigned long long* __restrict__ sbuf,
            const unsigned* __restrict__ epoch) {
    __shared__ float rp[2 * G * Hc];     // [parity][b][512]
    __shared__ float pl[16 * PLS];       // [wave][ob*32+ohl] matvec partials

    const int tid   = threadIdx.x;
    const int s     = blockIdx.x >> 4;   // h-slice 0..15
    const int gb    = blockIdx.x & 15;   // batch group 0..15
    const int kc    = tid >> 4;          // k-chunk 0..63 (8 k each)
    const int hg    = tid & 15;          // row-pair 0..15
    const int hbase = s * HS;
    const int b0    = gb * G;
    const unsigned ep = *epoch;

    // --- W tile: 2 rows x 8 k = 16 floats via OPAQUE asm loads (no remat) ---
    const float* Wp0 = WH + (size_t)(hbase + 2 * hg) * Hc + kc * 8; // row pair base
    float4 w00, w01, w10, w11;
    asm volatile(
        "global_load_dwordx4 %0, %4, off\n\t"
        "global_load_dwordx4 %1, %4, off offset:16\n\t"
        "global_load_dwordx4 %2, %4, off offset:2048\n\t"
        "global_load_dwordx4 %3, %4, off offset:2064\n\t"
        "s_waitcnt vmcnt(0)"
        : "=&v"(w00), "=&v"(w01), "=&v"(w10), "=&v"(w11)
        : "v"(Wp0) : "memory");

    // --- r_0 into parity-0 (same for all 4 batches) ---
    if (tid < Hc) {
        const float rv0 = tanhf(h0[tid]);
        #pragma unroll
        for (int b = 0; b < G; ++b) rp[b * Hc + tid] = rv0;
    }

    // --- owners: tid<128, ob = tid>>5 (batch), ohl = tid&31 (row) ---
    const bool own = (tid < 128);
    const int  ob  = tid >> 5;
    const int  ohl = tid & 31;
    const int  ohm = hbase + ohl;
    float hstate = 0.f, wi0 = 0.f, wi1 = 0.f, wi2 = 0.f, wo_own = 0.f;
    const float* noise_b = nullptr;
    const float* inp_b   = nullptr;
    float nz = 0.f, i0 = 0.f, i1 = 0.f, i2 = 0.f;
    if (own) {
        hstate = h0[ohm];
        wi0 = w_i[0 * Hc + ohm] * s_i[0];
        wi1 = w_i[1 * Hc + ohm] * s_i[1];
        wi2 = w_i[2 * Hc + ohm] * s_i[2];
        wo_own = w_o[ohm] * s_o[0] * (1.0f / Hc);
        noise_b = noise + (size_t)(b0 + ob) * Tc * Hc;
        inp_b   = input + (size_t)(b0 + ob) * Tc * Ic;
        nz = noise_b[ohm];
        i0 = inp_b[0]; i1 = inp_b[1]; i2 = inp_b[2];
    }

    // --- sweepers: waves 12-15 (tid>=768). lane i owns words {j*256+i} ---
    const bool swp = (tid >= 768);
    const int  si  = tid - 768;          // 0..255

    unsigned long long* sb_g = sbuf + (size_t)gb * (2 * G * Hc);
    float* part_b = part + ((size_t)s * Bc + b0) * Tc;

    __syncthreads();

    for (int t = 0; t < Tc; ++t) {
        const int par  = t & 1;
        const int par1 = (t + 1) & 1;

        // owners: prefetch next step's drive
        const int tn = (t + 1 < Tc) ? t + 1 : t;
        float nz_n = 0.f, i0n = 0.f, i1n = 0.f, i2n = 0.f;
        if (own) {
            nz_n = noise_b[(size_t)tn * Hc + ohm];
            i0n = inp_b[tn * Ic + 0];
            i1n = inp_b[tn * Ic + 1];
            i2n = inp_b[tn * Ic + 2];
        }

        // --- matvec: W in regs, r broadcast from LDS (round-8 verbatim) ---
        const float* rbp = rp + par * (G * Hc) + kc * 8;
        float a00 = 0.f, a01 = 0.f, a02 = 0.f, a03 = 0.f;
        float a10 = 0.f, a11 = 0.f, a12 = 0.f, a13 = 0.f;
        {
            const float4 r0 = *(const float4*)(rbp + 0 * Hc);
            const float4 r1 = *(const float4*)(rbp + 1 * Hc);
            const float4 r2 = *(const float4*)(rbp + 2 * Hc);
            const float4 r3 = *(const float4*)(rbp + 3 * Hc);
            DOT4(a00, w00, r0); DOT4(a01, w00, r1); DOT4(a02, w00, r2); DOT4(a03, w00, r3);
            DOT4(a10, w10, r0); DOT4(a11, w10, r1); DOT4(a12, w10, r2); DOT4(a13, w10, r3);
        }
        {
            const float4 r0 = *(const float4*)(rbp + 0 * Hc + 4);
            const float4 r1 = *(const float4*)(rbp + 1 * Hc + 4);
            const float4 r2 = *(const float4*)(rbp + 2 * Hc + 4);
            const float4 r3 = *(const float4*)(rbp + 3 * Hc + 4);
            DOT4(a00, w01, r0); DOT4(a01, w01, r1); DOT4(a02, w01, r2); DOT4(a03, w01, r3);
            DOT4(a10, w11, r0); DOT4(a11, w11, r1); DOT4(a12, w11, r2); DOT4(a13, w11, r3);
        }
        #define RED2(a) { a += __shfl_xor(a, 16, 64); a += __shfl_xor(a, 32, 64); }
        RED2(a00) RED2(a01) RED2(a02) RED2(a03)
        RED2(a10) RED2(a11) RED2(a12) RED2(a13)
        #undef RED2

        // writers: lane hg of each wave, transposed pl layout (conflict-free)
        if ((tid & 63) < 16) {
            float* plw = pl + (tid >> 6) * PLS;
            const int r0i = 2 * hg, r1i = 2 * hg + 1;
            plw[0 * 32 + r0i] = a00; plw[1 * 32 + r0i] = a01;
            plw[2 * 32 + r0i] = a02; plw[3 * 32 + r0i] = a03;
            plw[0 * 32 + r1i] = a10; plw[1 * 32 + r1i] = a11;
            plw[2 * 32 + r1i] = a12; plw[3 * 32 + r1i] = a13;
        }
        __syncthreads();                                   // B1: pl ready

        const unsigned want = ep + (unsigned)(t + 1);
        unsigned long long* slot = sb_g + (size_t)par1 * (G * Hc);
        float* wp_ = rp + par1 * (G * Hc);

        if (own) {
            float y = 0.f;
            #pragma unroll
            for (int w = 0; w < 16; ++w) y += pl[w * PLS + ob * 32 + ohl];
            const float di = i0 * wi0 + i1 * wi1 + i2 * wi2;
            hstate = hstate + (NS * nz + AL * di) + AL * (y - hstate);
            const float rv = tanhf(hstate);
            __hip_atomic_store(&slot[ob * Hc + ohm],
                               ((unsigned long long)want << 32) |
                               (unsigned long long)__float_as_uint(rv),
                               __ATOMIC_RELAXED, __HIP_MEMORY_SCOPE_AGENT);
            // output partial (off the exchange critical path)
            float pr = rv * wo_own;
            #pragma unroll
            for (int m = 16; m; m >>= 1) pr += __shfl_xor(pr, m, 32);
            if ((tid & 31) == 0) part_b[(size_t)ob * Tc + t] = pr;
        }

        // --- sweepers: coalesced 8-deep pipelined bursts until all tags match
        if (swp) {
            const unsigned long long* sp0 = slot + si;          // j=0,1
            const unsigned long long* sp1 = sp0 + 512;          // j=2,3
            const unsigned long long* sp2 = sp0 + 1024;         // j=4,5
            const unsigned long long* sp3 = sp0 + 1536;         // j=6,7
            unsigned long long v0, v1, v2, v3, v4, v5, v6, v7;
            for (;;) {
                asm volatile(
                    "global_load_dwordx2 %0, %8, off sc0 sc1\n\t"
                    "global_load_dwordx2 %1, %8, off offset:2048 sc0 sc1\n\t"
                    "global_load_dwordx2 %2, %9, off sc0 sc1\n\t"
                    "global_load_dwordx2 %3, %9, off offset:2048 sc0 sc1\n\t"
                    "global_load_dwordx2 %4, %10, off sc0 sc1\n\t"
                    "global_load_dwordx2 %5, %10, off offset:2048 sc0 sc1\n\t"
                    "global_load_dwordx2 %6, %11, off sc0 sc1\n\t"
                    "global_load_dwordx2 %7, %11, off offset:2048 sc0 sc1\n\t"
                    "s_waitcnt vmcnt(0)"
                    : "=&v"(v0), "=&v"(v1), "=&v"(v2), "=&v"(v3),
                      "=&v"(v4), "=&v"(v5), "=&v"(v6), "=&v"(v7)
                    : "v"(sp0), "v"(sp1), "v"(sp2), "v"(sp3)
                    : "memory");
                const bool ok =
                    ((unsigned)(v0 >> 32) == want) & ((unsigned)(v1 >> 32) == want) &
                    ((unsigned)(v2 >> 32) == want) & ((unsigned)(v3 >> 32) == want) &
                    ((unsigned)(v4 >> 32) == want) & ((unsigned)(v5 >> 32) == want) &
                    ((unsigned)(v6 >> 32) == want) & ((unsigned)(v7 >> 32) == want);
                if (ok) break;
                __builtin_amdgcn_s_sleep(1);
            }
            wp_[si +    0] = __uint_as_float((unsigned)v0);
            wp_[si +  256] = __uint_as_float((unsigned)v1);
            wp_[si +  512] = __uint_as_float((unsigned)v2);
            wp_[si +  768] = __uint_as_float((unsigned)v3);
            wp_[si + 1024] = __uint_as_float((unsigned)v4);
            wp_[si + 1280] = __uint_as_float((unsigned)v5);
            wp_[si + 1536] = __uint_as_float((unsigned)v6);
            wp_[si + 1792] = __uint_as_float((unsigned)v7);
        }
        __syncthreads();                                   // B2: r_{t+1} ready

        nz = nz_n; i0 = i0n; i1 = i1n; i2 = i2n;
    }
}

// ---------------------------------------------------------------------------
// Epilogue: out[b][t] = sum over 16 slices of part[s][b][t]
// ---------------------------------------------------------------------------
__global__ void out_reduce16(const float* __restrict__ part, float* __restrict__ out) {
    const int id = blockIdx.x * 256 + threadIdx.x;
    if (id >= Bc * Tc) return;
    const int b = id >> 11, t = id & (Tc - 1);
    float sm = 0.f;
    #pragma unroll
    for (int sl = 0; sl < 16; ++sl)
        sm += part[((size_t)sl * Bc + b) * Tc + t];
    out[id] = sm;
}

// ---------------------------------------------------------------------------
// Fallback (round-1 kernel) if d_ws is too small — safety net.
// ---------------------------------------------------------------------------
__launch_bounds__(512)
__global__ void rnn_scan_fb(const float* __restrict__ input, const float* __restrict__ noise,
                            const float* __restrict__ w_i, const float* __restrict__ s_i,
                            const float* __restrict__ WT, const float* __restrict__ w_o,
                            const float* __restrict__ s_o, const float* __restrict__ h0,
                            float* __restrict__ out) {
    __shared__ float r_lds[Hc];
    __shared__ float pl[4][Hc];
    __shared__ float wi_lds[Ic][Hc];
    __shared__ float red[8];

    const int tid = threadIdx.x;
    const int b   = blockIdx.x;
    const int g   = tid >> 7;
    const int j   = tid & 127;

    for (int i = 0; i < Ic; ++i) wi_lds[i][tid] = w_i[i * Hc + tid] * s_i[i];

    float h = h0[tid];
    float r_cur = tanhf(h);
    const float wo_h = w_o[tid] * s_o[0] * (1.0f / Hc);
    const float* noise_b = noise + (size_t)b * Tc * Hc;
    const float* inp_b   = input + (size_t)b * Tc * Ic;
    float nz = noise_b[tid];
    float i0 = inp_b[0], i1 = inp_b[1], i2 = inp_b[2];
    const float* Wg = WT + (g * 128) * Hc + 4 * j;
    const float* rg = r_lds + g * 128;
    __syncthreads();

    for (int t = 0; t < Tc; ++t) {
        const int tn = (t + 1 < Tc) ? t + 1 : t;
        const float nz_n = noise_b[(size_t)tn * Hc + tid];
        const float i0n = inp_b[tn * Ic + 0];
        const float i1n = inp_b[tn * Ic + 1];
        const float i2n = inp_b[tn * Ic + 2];

        r_lds[tid] = r_cur;
        __syncthreads();
        float a0 = 0.f, a1 = 0.f, a2 = 0.f, a3 = 0.f;
        #pragma unroll 4
        for (int kk = 0; kk < 128; kk += 4) {
            const float4 rv = *(const float4*)(rg + kk);
            const float4 w0 = *(const float4*)(Wg + (kk + 0) * Hc);
            const float4 w1 = *(const float4*)(Wg + (kk + 1) * Hc);
            const float4 w2 = *(const float4*)(Wg + (kk + 2) * Hc);
            const float4 w3 = *(const float4*)(Wg + (kk + 3) * Hc);
            a0 = fmaf(rv.x, w0.x, a0); a0 = fmaf(rv.y, w1.x, a0);
            a0 = fmaf(rv.z, w2.x, a0); a0 = fmaf(rv.w, w3.x, a0);
            a1 = fmaf(rv.x, w0.y, a1); a1 = fmaf(rv.y, w1.y, a1);
            a1 = fmaf(rv.z, w2.y, a1); a1 = fmaf(rv.w, w3.y, a1);
            a2 = fmaf(rv.x, w0.z, a2); a2 = fmaf(rv.y, w1.z, a2);
            a2 = fmaf(rv.z, w2.z, a2); a2 = fmaf(rv.w, w3.z, a2);
            a3 = fmaf(rv.x, w0.w, a3); a3 = fmaf(rv.y, w1.w, a3);
            a3 = fmaf(rv.z, w2.w, a3); a3 = fmaf(rv.w, w3.w, a3);
        }
        *(float4*)&pl[g][4 * j] = make_float4(a0, a1, a2, a3);
        __syncthreads();

        const float y  = pl[0][tid] + pl[1][tid] + pl[2][tid] + pl[3][tid];
        const float di = i0 * wi_lds[0][tid] + i1 * wi_lds[1][tid] + i2 * wi_lds[2][tid];
        h = h + (NS * nz + AL * di) + AL * (y - h);
        r_cur = tanhf(h);

        float p = r_cur * wo_h;
        #pragma unroll
        for (int off = 32; off; off >>= 1) p += __shfl_xor(p, off, 64);
        if ((tid & 63) == 0) red[tid >> 6] = p;
        __syncthreads();
        if (tid == 0)
            out[(size_t)b * Tc + t] = red[0] + red[1] + red[2] + red[3] +
                                      red[4] + red[5] + red[6] + red[7];
        nz = nz_n; i0 = i0n; i1 = i1n; i2 = i2n;
    }
}

extern "C" void kernel_launch(void* const* d_in, const int* in_sizes, int n_in,
                              void* d_out, int out_size, void* d_ws, size_t ws_size,
                              hipStream_t stream) {
    (void)n_in; (void)out_size;
    const float* input     = (const float*)d_in[0];
    const float* noise     = (const float*)d_in[1];
    const float* w_i       = (const float*)d_in[2];
    const float* s_i       = (const float*)d_in[3];
    const float* m_rec     = (const float*)d_in[4];
    const float* n_rec     = (const float*)d_in[5];
    const float* rec_noise = (const float*)d_in[6];
    const float* w_o       = (const float*)d_in[7];
    const float* s_o       = (const float*)d_in[8];
    const float* h0        = (const float*)d_in[9];
    float* out = (float*)d_out;

    const int R = in_sizes[4] / Hc;
    char* ws = (char*)d_ws;

    if (ws_size >= WS_NEED) {
        float* WH = (float*)(ws + WS_WH);
        unsigned long long* sbuf = (unsigned long long*)(ws + WS_SBUF);
        float* part = (float*)(ws + WS_PART);
        unsigned* epoch = (unsigned*)(ws + WS_EPOCH);

        bump_epoch<<<1, 1, 0, stream>>>(epoch);   // stale tags can never match
        prep_wh<<<(Hc * Hc + 255) / 256, 256, 0, stream>>>(m_rec, n_rec, rec_noise, WH, R);
        rnn16s<<<256, 1024, 0, stream>>>(input, noise, w_i, s_i, WH, w_o, s_o, h0,
                                         part, sbuf, epoch);
        out_reduce16<<<(Bc * Tc + 255) / 256, 256, 0, stream>>>(part, out);
    } else {
        float* WT = (float*)(ws + WS_WH);
        prep_wt<<<(Hc * Hc + 255) / 256, 256, 0, stream>>>(m_rec, n_rec, rec_noise, WT, R);
        rnn_scan_fb<<<Bc, 512, 0, stream>>>(input, noise, w_i, s_i, WT, w_o, s_o, h0, out);
    }
}